// Round 6
// baseline (567.828 us; speedup 1.0000x reference)
//
#include <hip/hip_runtime.h>

typedef unsigned short u16;
typedef unsigned int u32;
typedef unsigned long long u64;

typedef float f32x4 __attribute__((ext_vector_type(4)));
typedef __bf16 bf16x8 __attribute__((ext_vector_type(8)));
typedef u16 u16x4 __attribute__((ext_vector_type(4)));
typedef u16 u16x8 __attribute__((ext_vector_type(8)));
typedef float fx4 __attribute__((ext_vector_type(4)));

// Problem constants: B=1, S=2048, D=4096, H=32, KV=8, HD=128, REP=4.

static __device__ __forceinline__ u16 f2b(float f) {
  u32 u = __builtin_bit_cast(u32, f);
  return (u16)((u + 0x7fffu + ((u >> 16) & 1u)) >> 16);  // RNE
}
static __device__ __forceinline__ float b2f(u16 b) {
  return __builtin_bit_cast(float, ((u32)b) << 16);
}
// global -> LDS direct copy, 16B per lane. LDS dest must be linear in lane.
static __device__ __forceinline__ void gload_lds16(const void* g, void* l) {
  auto gp = (const __attribute__((address_space(1))) u32*)(u64)g;
  auto lp = (__attribute__((address_space(3))) u32*)(u32)(u64)l;
  __builtin_amdgcn_global_load_lds(gp, lp, 16, 0, 0);
}

// ---------------- f32 -> bf16 cast ----------------
__global__ __launch_bounds__(256) void cast_bf16_kernel(const float* __restrict__ in,
                                                        u16* __restrict__ out) {
  size_t i = (size_t)(blockIdx.x * 256 + threadIdx.x) * 4;
  fx4 v = *(const fx4*)(in + i);
  u16x4 o;
  o[0] = f2b(v[0]); o[1] = f2b(v[1]); o[2] = f2b(v[2]); o[3] = f2b(v[3]);
  *(u16x4*)(out + i) = o;
}

// ---------------- weight cast + transpose: in [K][N] f32 -> out [N][K] bf16 ----------------
__global__ __launch_bounds__(256) void wtrans_kernel(const float* __restrict__ in,
                                                     u16* __restrict__ out, int K, int N) {
  __shared__ float tile[32][33];
  int n0 = blockIdx.x * 32, k0 = blockIdx.y * 32;
  int t = threadIdx.x;
  int r = t >> 3, c4 = (t & 7) * 4;
  fx4 v = *(const fx4*)(in + (size_t)(k0 + r) * N + n0 + c4);
  tile[r][c4 + 0] = v[0]; tile[r][c4 + 1] = v[1];
  tile[r][c4 + 2] = v[2]; tile[r][c4 + 3] = v[3];
  __syncthreads();
  u16x4 o;
  o[0] = f2b(tile[c4 + 0][r]); o[1] = f2b(tile[c4 + 1][r]);
  o[2] = f2b(tile[c4 + 2][r]); o[3] = f2b(tile[c4 + 3][r]);
  *(u16x4*)(out + (size_t)(n0 + r) * K + k0 + c4) = o;
}

// ---------------- RoPE in-place on bf16 [S][*], row stride LD, NH heads ----------------
template <int NH, int LD>
__global__ __launch_bounds__(256) void rope_kernel(u16* __restrict__ x,
                                                   const float* __restrict__ cosb,
                                                   const float* __restrict__ sinb) {
  int tid = blockIdx.x * 256 + threadIdx.x;
  int s = tid / (NH * 16);
  int rem = tid % (NH * 16);
  int h = rem >> 4, c = rem & 15;
  u16* p = x + (size_t)s * LD + h * 128 + c * 8;
  u16x8 v = *(const u16x8*)p;
  fx4 cs = *(const fx4*)(cosb + s * 64 + c * 4);
  fx4 sn = *(const fx4*)(sinb + s * 64 + c * 4);
  u16x8 o;
#pragma unroll
  for (int j = 0; j < 4; ++j) {
    float a = b2f(v[2 * j]), b = b2f(v[2 * j + 1]);
    o[2 * j]     = f2b(a * cs[j] - b * sn[j]);
    o[2 * j + 1] = f2b(a * sn[j] + b * cs[j]);
  }
  *(u16x8*)p = o;
}

// ---------------- V transpose: vb [2048][.] (stride 6144) -> vT [8][128][2048] ----------------
__global__ __launch_bounds__(256) void vtrans_kernel(const u16* __restrict__ vb,
                                                     u16* __restrict__ vT) {
  __shared__ u16 tile[64][72];
  int s0 = blockIdx.x * 64;
  int d0 = blockIdx.y * 64;
  int h  = blockIdx.z;
  int t = threadIdx.x;
#pragma unroll
  for (int it = 0; it < 2; ++it) {
    int lin = it * 2048 + t * 8;
    int r = lin >> 6, c = lin & 63;
    u16x8 v = *(const u16x8*)(vb + (size_t)(s0 + r) * 6144 + h * 128 + d0 + c);
#pragma unroll
    for (int j = 0; j < 8; ++j) tile[r][c + j] = v[j];
  }
  __syncthreads();
#pragma unroll
  for (int it = 0; it < 2; ++it) {
    int lin = it * 2048 + t * 8;
    int dd = lin >> 6, ss = lin & 63;
    u16x8 o;
#pragma unroll
    for (int j = 0; j < 8; ++j) o[j] = tile[ss + j][dd];
    *(u16x8*)(vT + (size_t)h * 262144 + (size_t)(d0 + dd) * 2048 + s0 + ss) = o;
  }
}

// ---------------- deep-pipelined bf16 GEMM: C[M][N] = A[M][K] * Bt[N][K]^T ----------------
// BM=128, BN=256, BK=64 split in two 32-k halves. 8 waves (2M x 4N), 512 thr.
// Phase = one kh half: 8 ds_read_b128 + 1 half-stage + barrier + 16 MFMA + vmcnt(6) + barrier.
// Double-buffered LDS; counted vmcnt (never 0 in main loop); raw s_barrier (no drain).
// Paired-row LDS layout: addr(r,c) = (r>>1)*128 + ((r&1)*4 + (c ^ ((r>>1)&3)))*16
// -> 16-consecutive-row ds_read_b128 hits 8 distinct 16B slots (2-way = free).
#define SWA(r, c) (((r) >> 1) * 128 + ((((r) & 1) * 4 + ((c) ^ (((r) >> 1) & 3))) << 4))
template <int OUT_BF16>
__global__ __launch_bounds__(512, 1) void gemm8_kernel(const u16* __restrict__ A,
                                                       const u16* __restrict__ Bt,
                                                       void* __restrict__ Cv,
                                                       int M, int N, int K) {
  __shared__ u16 sA[2][2][4096];   // [dbuf][kh][128 rows x 32 k]  8KB each
  __shared__ u16 sB[2][2][8192];   // [dbuf][kh][256 rows x 32 k] 16KB each
  const int tid = threadIdx.x;
  const int lane = tid & 63;
  const int w = tid >> 6;
  const int wm = w >> 2, wn = w & 3;
  const int l15 = lane & 15, l4 = lane >> 4;
  // XCD-aware bijective swizzle (gridDim.x % 8 == 0); mi fastest -> share Bt panel.
  const int cpx = gridDim.x >> 3;
  const int swz = ((int)blockIdx.x & 7) * cpx + ((int)blockIdx.x >> 3);
  const int m0 = (swz & 15) * 128;
  const int n0 = (swz >> 4) * 256;

  f32x4 acc[4][4] = {};

  // stage one kh-half of tile stT (A: 1 load, B: 2 loads per thread)
  auto STAGE = [&](int stT, int stKh) {
    int sd = stT & 1;
    {
      int off = tid * 16;
      int L = off >> 7, s = (off >> 4) & 7;
      int r = 2 * L + (s >> 2), c = (s & 3) ^ (L & 3);
      gload_lds16(A + (size_t)(m0 + r) * K + stT * 64 + stKh * 32 + c * 8,
                  (char*)&sA[sd][stKh][0] + off);
    }
#pragma unroll
    for (int u = 0; u < 2; ++u) {
      int off = tid * 16 + u * 8192;
      int L = off >> 7, s = (off >> 4) & 7;
      int r = 2 * L + (s >> 2), c = (s & 3) ^ (L & 3);
      gload_lds16(Bt + (size_t)(n0 + r) * K + stT * 64 + stKh * 32 + c * 8,
                  (char*)&sB[sd][stKh][0] + off);
    }
  };

  // one phase: ds_read 8 frags of [d][kh], optional stage, barrier, 16 MFMA
  auto PHASE = [&](int d, int kh, int stT, int stKh, bool doStage) {
    const char* aB = (const char*)&sA[d][kh][0];
    const char* bB = (const char*)&sB[d][kh][0];
    bf16x8 av[4], bv[4];
#pragma unroll
    for (int f = 0; f < 4; ++f) {
      av[f] = *(const bf16x8*)(aB + SWA(wm * 64 + f * 16 + l15, l4));
      bv[f] = *(const bf16x8*)(bB + SWA(wn * 64 + f * 16 + l15, l4));
    }
    if (doStage) STAGE(stT, stKh);
    __builtin_amdgcn_s_barrier();
    asm volatile("s_waitcnt lgkmcnt(0)" ::: "memory");
    __builtin_amdgcn_sched_barrier(0);
    __builtin_amdgcn_s_setprio(1);
#pragma unroll
    for (int fi = 0; fi < 4; ++fi)
#pragma unroll
      for (int fj = 0; fj < 4; ++fj)
        acc[fi][fj] = __builtin_amdgcn_mfma_f32_16x16x32_bf16(av[fi], bv[fj], acc[fi][fj], 0, 0, 0);
    __builtin_amdgcn_s_setprio(0);
    __builtin_amdgcn_sched_barrier(0);
  };

  const int nt = K >> 6;  // 64 K-tiles at K=4096
  // prologue: kh0(0), kh1(0), kh0(1) = 9 loads/thread; wait first 3 retired
  STAGE(0, 0);
  STAGE(0, 1);
  STAGE(1, 0);
  asm volatile("s_waitcnt vmcnt(6)" ::: "memory");
  __builtin_amdgcn_s_barrier();

  for (int t = 0; t < nt - 2; ++t) {
    PHASE(t & 1, 0, t + 1, 1, true);            // reads kh0(t); stages kh1(t+1)
    asm volatile("s_waitcnt vmcnt(6)" ::: "memory");
    __builtin_amdgcn_s_barrier();
    PHASE(t & 1, 1, t + 2, 0, true);            // reads kh1(t); stages kh0(t+2)
    asm volatile("s_waitcnt vmcnt(6)" ::: "memory");
    __builtin_amdgcn_s_barrier();
  }
  {  // t = nt-2: stage kh1(nt-1) only
    int t = nt - 2;
    PHASE(t & 1, 0, t + 1, 1, true);
    asm volatile("s_waitcnt vmcnt(6)" ::: "memory");
    __builtin_amdgcn_s_barrier();
    PHASE(t & 1, 1, 0, 0, false);
    asm volatile("s_waitcnt vmcnt(3)" ::: "memory");
    __builtin_amdgcn_s_barrier();
  }
  {  // t = nt-1: epilogue drain
    int t = nt - 1;
    PHASE(t & 1, 0, 0, 0, false);
    asm volatile("s_waitcnt vmcnt(0)" ::: "memory");
    __builtin_amdgcn_s_barrier();
    PHASE(t & 1, 1, 0, 0, false);
  }

#pragma unroll
  for (int fi = 0; fi < 4; ++fi)
#pragma unroll
    for (int fj = 0; fj < 4; ++fj) {
      int col = n0 + wn * 64 + fj * 16 + l15;
#pragma unroll
      for (int r = 0; r < 4; ++r) {
        int row = m0 + wm * 64 + fi * 16 + l4 * 4 + r;
        if (OUT_BF16) ((u16*)Cv)[(size_t)row * N + col] = f2b(acc[fi][fj][r]);
        else          ((float*)Cv)[(size_t)row * N + col] = acc[fi][fj][r];
      }
    }
}

// ---------------- Flash attention, causal, GQA (FROZEN from round 4) ----------------
__global__ __launch_bounds__(256) void attn_kernel(const u16* __restrict__ qkv,
                                                   const u16* __restrict__ vT,
                                                   u16* __restrict__ ob) {
  __shared__ u16 sK[2][64 * 128];   // [s][kd], 256B rows, chunk ^= (row&15)
  __shared__ u16 sV[2][64 * 128];   // [hd][s], 128B rows, chunk ^= (row&7)
  __shared__ u16 sP[4][32 * 64];    // per-wave P, 128B rows, chunk ^= (row&7)
  const int tid = threadIdx.x, lane = tid & 63, w = tid >> 6;
  const int l15 = lane & 15, l4 = lane >> 4;
  const int h = blockIdx.x;
  const int t = 15 - (int)blockIdx.y;     // heavy q-tiles dispatched first
  const int kvh = h >> 2;
  const int q0 = t * 128;
  const int nt = 2 * t + 2;               // kv tiles to process
  const float scale = 0.08838834764831845f;  // 1/sqrt(128)

  const u16* qb = qkv;            // q section, row stride 6144
  const u16* kb = qkv + 4096;     // k section, row stride 6144

  bf16x8 aq[2][4];
#pragma unroll
  for (int m = 0; m < 2; ++m)
#pragma unroll
    for (int kc = 0; kc < 4; ++kc)
      aq[m][kc] = *(const bf16x8*)(qb + (size_t)(q0 + w * 32 + m * 16 + l15) * 6144 +
                                   h * 128 + kc * 32 + l4 * 8);

  f32x4 o[2][8] = {};
  float mrun[2][4], lrun[2][4];
#pragma unroll
  for (int m = 0; m < 2; ++m)
#pragma unroll
    for (int i = 0; i < 4; ++i) { mrun[m][i] = -1e30f; lrun[m][i] = 0.f; }

  auto STAGE = [&](int b, int tt) {
    int s0 = tt * 64;
#pragma unroll
    for (int it = 0; it < 4; ++it) {
      int off = it * 4096 + tid * 16;
      int row = off >> 8;
      int c = ((off >> 4) & 15) ^ (row & 15);
      gload_lds16(kb + (size_t)(s0 + row) * 6144 + kvh * 128 + c * 8, (char*)sK[b] + off);
    }
#pragma unroll
    for (int it = 0; it < 4; ++it) {
      int off = it * 4096 + tid * 16;
      int row = off >> 7;
      int c = ((off >> 4) & 7) ^ (row & 7);
      gload_lds16(vT + (size_t)kvh * 262144 + (size_t)row * 2048 + s0 + c * 8,
                  (char*)sV[b] + off);
    }
  };

  STAGE(0, 0);
  __syncthreads();
  int cur = 0;

  for (int tt = 0; tt < nt; ++tt) {
    if (tt + 1 < nt) STAGE(cur ^ 1, tt + 1);
    int s0 = tt * 64;
    u16* wp = &sP[w][0];

#pragma unroll
    for (int m = 0; m < 2; ++m) {
      const int frow0 = q0 + w * 32 + m * 16;
      if (s0 > frow0 + 15) continue;
      const bool has_mask = (s0 + 63 > frow0);

      f32x4 sf[4] = {};
#pragma unroll
      for (int kc = 0; kc < 4; ++kc) {
#pragma unroll
        for (int j = 0; j < 4; ++j) {
          int krow = j * 16 + l15;
          bf16x8 bk = *(const bf16x8*)((char*)sK[cur] + krow * 256 +
                                       (((kc * 4 + l4) ^ (krow & 15)) << 4));
          sf[j] = __builtin_amdgcn_mfma_f32_16x16x32_bf16(aq[m][kc], bk, sf[j], 0, 0, 0);
        }
      }

      const int qrow_base = frow0 + l4 * 4;
      float pv[4][4], mloc[4], lsum[4];
#pragma unroll
      for (int i = 0; i < 4; ++i) mloc[i] = -1e30f;
#pragma unroll
      for (int j = 0; j < 4; ++j) {
        int col = s0 + j * 16 + l15;
#pragma unroll
        for (int i = 0; i < 4; ++i) {
          float v = sf[j][i] * scale;
          if (has_mask && col > qrow_base + i) v = -1e9f;
          pv[j][i] = v;
          mloc[i] = fmaxf(mloc[i], v);
        }
      }
#pragma unroll
      for (int off = 1; off < 16; off <<= 1)
#pragma unroll
        for (int i = 0; i < 4; ++i) mloc[i] = fmaxf(mloc[i], __shfl_xor(mloc[i], off, 64));
      float alpha[4];
#pragma unroll
      for (int i = 0; i < 4; ++i) {
        float mn = fmaxf(mrun[m][i], mloc[i]);
        alpha[i] = __expf(mrun[m][i] - mn);
        mrun[m][i] = mn;
        lsum[i] = 0.f;
      }
#pragma unroll
      for (int j = 0; j < 4; ++j)
#pragma unroll
        for (int i = 0; i < 4; ++i) {
          float p = __expf(pv[j][i] - mrun[m][i]);
          pv[j][i] = p;
          lsum[i] += p;
        }
#pragma unroll
      for (int off = 1; off < 16; off <<= 1)
#pragma unroll
        for (int i = 0; i < 4; ++i) lsum[i] += __shfl_xor(lsum[i], off, 64);
#pragma unroll
      for (int i = 0; i < 4; ++i) lrun[m][i] = lrun[m][i] * alpha[i] + lsum[i];
#pragma unroll
      for (int n = 0; n < 8; ++n)
#pragma unroll
        for (int i = 0; i < 4; ++i) o[m][n][i] *= alpha[i];

#pragma unroll
      for (int j = 0; j < 4; ++j)
#pragma unroll
        for (int i = 0; i < 4; ++i) {
          int r = m * 16 + l4 * 4 + i;
          int colb = (j * 16 + l15) * 2;
          *(u16*)((char*)wp + r * 128 + (colb ^ ((r & 7) << 4))) = f2b(pv[j][i]);
        }
#pragma unroll
      for (int ks = 0; ks < 2; ++ks) {
        int prow = m * 16 + l15;
        int pb = (ks * 32 + l4 * 8) * 2;
        bf16x8 pa = *(const bf16x8*)((char*)wp + prow * 128 + (pb ^ ((prow & 7) << 4)));
#pragma unroll
        for (int n = 0; n < 8; ++n) {
          int vrow = n * 16 + l15;
          bf16x8 vv = *(const bf16x8*)((char*)sV[cur] + vrow * 128 +
                                       (((ks * 4 + l4) ^ (vrow & 7)) << 4));
          o[m][n] = __builtin_amdgcn_mfma_f32_16x16x32_bf16(pa, vv, o[m][n], 0, 0, 0);
        }
      }
    }
    __syncthreads();
    cur ^= 1;
  }

#pragma unroll
  for (int m = 0; m < 2; ++m) {
    float rcp[4];
#pragma unroll
    for (int i = 0; i < 4; ++i) rcp[i] = 1.f / lrun[m][i];
#pragma unroll
    for (int n = 0; n < 8; ++n)
#pragma unroll
      for (int i = 0; i < 4; ++i) {
        int row = q0 + w * 32 + m * 16 + l4 * 4 + i;
        int col = h * 128 + n * 16 + l15;
        ob[(size_t)row * 4096 + col] = f2b(o[m][n][i] * rcp[i]);
      }
  }
}

extern "C" void kernel_launch(void* const* d_in, const int* in_sizes, int n_in,
                              void* d_out, int out_size, void* d_ws, size_t ws_size,
                              hipStream_t stream) {
  const float* x  = (const float*)d_in[0];
  const float* fc = (const float*)d_in[1];
  const float* fs = (const float*)d_in[2];
  // d_in[3] = mask (causal, hardcoded); d_in[8] = start_pos (0)
  const float* wq = (const float*)d_in[4];
  const float* wk = (const float*)d_in[5];
  const float* wv = (const float*)d_in[6];
  const float* wo = (const float*)d_in[7];
  float* out = (float*)d_out;
  char* ws = (char*)d_ws;

  // workspace layout (~113 MB)
  u16* xb   = (u16*)(ws + 0);               // 16.8 MB  x bf16 [2048][4096]
  u16* qkv  = (u16*)(ws + 16777216);        // 25.2 MB  qkv bf16 [2048][6144]
  u16* ob   = (u16*)(ws + 41943040);        // 16.8 MB  attn out bf16 [2048][4096]
  u16* wT   = (u16*)(ws + 58720256);        // 50.3 MB  w_qkv^T bf16 [6144][4096]
  u16* vT   = (u16*)(ws + 109051904);       //  4.2 MB  v^T bf16 [8][128][2048]
  u16* woT  = wT;                           // reuse (wT dead after qkv GEMM)

  cast_bf16_kernel<<<8192, 256, 0, stream>>>(x, xb);
  wtrans_kernel<<<dim3(128, 128), 256, 0, stream>>>(wq, wT, 4096, 4096);
  wtrans_kernel<<<dim3(32, 128), 256, 0, stream>>>(wk, wT + (size_t)4096 * 4096, 4096, 1024);
  wtrans_kernel<<<dim3(32, 128), 256, 0, stream>>>(wv, wT + (size_t)5120 * 4096, 4096, 1024);

  // fused qkv projection: [2048][6144]; grid 16x24 = 384 (%8==0)
  gemm8_kernel<1><<<384, 512, 0, stream>>>(xb, wT, qkv, 2048, 6144, 4096);

  rope_kernel<32, 6144><<<4096, 256, 0, stream>>>(qkv, fc, fs);
  rope_kernel<8, 6144><<<1024, 256, 0, stream>>>(qkv + 4096, fc, fs);
  vtrans_kernel<<<dim3(32, 2, 8), 256, 0, stream>>>(qkv + 5120, vT);

  attn_kernel<<<dim3(32, 16), 256, 0, stream>>>(qkv, vT, ob);

  wtrans_kernel<<<dim3(128, 128), 256, 0, stream>>>(wo, woT, 4096, 4096);
  // out projection: grid 16x16 = 256 (%8==0)
  gemm8_kernel<0><<<256, 512, 0, stream>>>(ob, woT, out, 2048, 4096, 4096);
}

// Round 7
// 533.623 us; speedup vs baseline: 1.0641x; 1.0641x over previous
//
#include <hip/hip_runtime.h>

typedef unsigned short u16;
typedef unsigned int u32;
typedef unsigned long long u64;

typedef float f32x4 __attribute__((ext_vector_type(4)));
typedef __bf16 bf16x8 __attribute__((ext_vector_type(8)));
typedef u16 u16x4 __attribute__((ext_vector_type(4)));
typedef u16 u16x8 __attribute__((ext_vector_type(8)));
typedef float fx4 __attribute__((ext_vector_type(4)));

// Problem constants: B=1, S=2048, D=4096, H=32, KV=8, HD=128, REP=4.

static __device__ __forceinline__ u16 f2b(float f) {
  u32 u = __builtin_bit_cast(u32, f);
  return (u16)((u + 0x7fffu + ((u >> 16) & 1u)) >> 16);  // RNE
}
static __device__ __forceinline__ float b2f(u16 b) {
  return __builtin_bit_cast(float, ((u32)b) << 16);
}
// global -> LDS direct copy, 16B per lane. LDS dest must be linear in lane.
static __device__ __forceinline__ void gload_lds16(const void* g, void* l) {
  auto gp = (const __attribute__((address_space(1))) u32*)(u64)g;
  auto lp = (__attribute__((address_space(3))) u32*)(u32)(u64)l;
  __builtin_amdgcn_global_load_lds(gp, lp, 16, 0, 0);
}

// ---------------- f32 -> bf16 cast ----------------
__global__ __launch_bounds__(256) void cast_bf16_kernel(const float* __restrict__ in,
                                                        u16* __restrict__ out) {
  size_t i = (size_t)(blockIdx.x * 256 + threadIdx.x) * 4;
  fx4 v = *(const fx4*)(in + i);
  u16x4 o;
  o[0] = f2b(v[0]); o[1] = f2b(v[1]); o[2] = f2b(v[2]); o[3] = f2b(v[3]);
  *(u16x4*)(out + i) = o;
}

// ---------------- weight cast + transpose: in [K][N] f32 -> out [N][K] bf16 ----------------
__global__ __launch_bounds__(256) void wtrans_kernel(const float* __restrict__ in,
                                                     u16* __restrict__ out, int K, int N) {
  __shared__ float tile[32][33];
  int n0 = blockIdx.x * 32, k0 = blockIdx.y * 32;
  int t = threadIdx.x;
  int r = t >> 3, c4 = (t & 7) * 4;
  fx4 v = *(const fx4*)(in + (size_t)(k0 + r) * N + n0 + c4);
  tile[r][c4 + 0] = v[0]; tile[r][c4 + 1] = v[1];
  tile[r][c4 + 2] = v[2]; tile[r][c4 + 3] = v[3];
  __syncthreads();
  u16x4 o;
  o[0] = f2b(tile[c4 + 0][r]); o[1] = f2b(tile[c4 + 1][r]);
  o[2] = f2b(tile[c4 + 2][r]); o[3] = f2b(tile[c4 + 3][r]);
  *(u16x4*)(out + (size_t)(n0 + r) * K + k0 + c4) = o;
}

// ---------------- RoPE in-place on bf16 [S][*], row stride LD, NH heads ----------------
template <int NH, int LD>
__global__ __launch_bounds__(256) void rope_kernel(u16* __restrict__ x,
                                                   const float* __restrict__ cosb,
                                                   const float* __restrict__ sinb) {
  int tid = blockIdx.x * 256 + threadIdx.x;
  int s = tid / (NH * 16);
  int rem = tid % (NH * 16);
  int h = rem >> 4, c = rem & 15;
  u16* p = x + (size_t)s * LD + h * 128 + c * 8;
  u16x8 v = *(const u16x8*)p;
  fx4 cs = *(const fx4*)(cosb + s * 64 + c * 4);
  fx4 sn = *(const fx4*)(sinb + s * 64 + c * 4);
  u16x8 o;
#pragma unroll
  for (int j = 0; j < 4; ++j) {
    float a = b2f(v[2 * j]), b = b2f(v[2 * j + 1]);
    o[2 * j]     = f2b(a * cs[j] - b * sn[j]);
    o[2 * j + 1] = f2b(a * sn[j] + b * cs[j]);
  }
  *(u16x8*)p = o;
}

// ---------------- V transpose: vb [2048][.] (stride 6144) -> vT [8][128][2048] ----------------
__global__ __launch_bounds__(256) void vtrans_kernel(const u16* __restrict__ vb,
                                                     u16* __restrict__ vT) {
  __shared__ u16 tile[64][72];
  int s0 = blockIdx.x * 64;
  int d0 = blockIdx.y * 64;
  int h  = blockIdx.z;
  int t = threadIdx.x;
#pragma unroll
  for (int it = 0; it < 2; ++it) {
    int lin = it * 2048 + t * 8;
    int r = lin >> 6, c = lin & 63;
    u16x8 v = *(const u16x8*)(vb + (size_t)(s0 + r) * 6144 + h * 128 + d0 + c);
#pragma unroll
    for (int j = 0; j < 8; ++j) tile[r][c + j] = v[j];
  }
  __syncthreads();
#pragma unroll
  for (int it = 0; it < 2; ++it) {
    int lin = it * 2048 + t * 8;
    int dd = lin >> 6, ss = lin & 63;
    u16x8 o;
#pragma unroll
    for (int j = 0; j < 8; ++j) o[j] = tile[ss + j][dd];
    *(u16x8*)(vT + (size_t)h * 262144 + (size_t)(d0 + dd) * 2048 + s0 + ss) = o;
  }
}

// ---------------- bf16 GEMM: C[M][N] = A[M][K] * Bt[N][K]^T (round-4 measured best) ----------
// 128x128 tile, BK=64, 4 waves, 1D grid with bijective XCD swizzle (nwg%8==0).
template <int OUT_BF16>
__global__ __launch_bounds__(256) void gemm_bt_kernel(const u16* __restrict__ A,
                                                      const u16* __restrict__ Bt,
                                                      void* __restrict__ Cv,
                                                      int M, int N, int K) {
  __shared__ u16 sA[128 * 64];
  __shared__ u16 sB[128 * 64];
  const int tid = threadIdx.x;
  const int lane = tid & 63;
  const int w = tid >> 6;
  const int wr = w >> 1, wc = w & 1;
  const int l15 = lane & 15, l4 = lane >> 4;
  const int cpx = gridDim.x >> 3;
  const int swz = ((int)blockIdx.x & 7) * cpx + ((int)blockIdx.x >> 3);
  const int m0 = (swz & 15) * 128;
  const int n0 = (swz >> 4) * 128;

  f32x4 acc[4][4] = {};

  for (int kt = 0; kt < K; kt += 64) {
#pragma unroll
    for (int it = 0; it < 4; ++it) {
      int off = it * 4096 + tid * 16;
      int row = off >> 7;
      int c = ((off >> 4) & 7) ^ (row & 7);
      gload_lds16(A + (size_t)(m0 + row) * K + kt + c * 8, (char*)sA + off);
      gload_lds16(Bt + (size_t)(n0 + row) * K + kt + c * 8, (char*)sB + off);
    }
    __syncthreads();
#pragma unroll
    for (int ks = 0; ks < 2; ++ks) {
      bf16x8 av[4], bv[4];
#pragma unroll
      for (int i = 0; i < 4; ++i) {
        int arow = wr * 64 + i * 16 + l15;
        av[i] = *(const bf16x8*)((char*)sA + arow * 128 + (((ks * 4 + l4) ^ (arow & 7)) << 4));
        int brow = wc * 64 + i * 16 + l15;
        bv[i] = *(const bf16x8*)((char*)sB + brow * 128 + (((ks * 4 + l4) ^ (brow & 7)) << 4));
      }
#pragma unroll
      for (int i = 0; i < 4; ++i)
#pragma unroll
        for (int j = 0; j < 4; ++j)
          acc[i][j] = __builtin_amdgcn_mfma_f32_16x16x32_bf16(av[i], bv[j], acc[i][j], 0, 0, 0);
    }
    __syncthreads();
  }

#pragma unroll
  for (int i = 0; i < 4; ++i)
#pragma unroll
    for (int j = 0; j < 4; ++j) {
      int col = n0 + wc * 64 + j * 16 + l15;
#pragma unroll
      for (int r = 0; r < 4; ++r) {
        int row = m0 + wr * 64 + i * 16 + l4 * 4 + r;
        if (OUT_BF16) ((u16*)Cv)[(size_t)row * N + col] = f2b(acc[i][j][r]);
        else          ((float*)Cv)[(size_t)row * N + col] = acc[i][j][r];
      }
    }
}

// ---------------- Flash attention, causal, GQA — swapped-QK^T transposed softmax ----------
// Grid: (32 heads, 16 q-tiles of 128 rows). 4 waves x 32 q-rows (2 fragments of 16).
// S^T = mfma(K,Q): lane owns q-row (col=l15); row reduce = in-lane + 2 shfl.
// O^T = mfma(V^T, P^T): per-lane scalar alpha/lrun; packed epilogue.
__global__ __launch_bounds__(256) void attn_kernel(const u16* __restrict__ qkv,
                                                   const u16* __restrict__ vT,
                                                   u16* __restrict__ ob) {
  __shared__ u16 sK[2][64 * 128];   // [s][kd], 256B rows, chunk ^= (row&15)
  __shared__ u16 sV[2][64 * 128];   // [hd][s], 128B rows, chunk ^= (row&7)
  __shared__ u16 sP[4][16 * 64];    // per-wave P^T [q=16][s=64], 128B rows, ^(q&7)<<4
  const int tid = threadIdx.x, lane = tid & 63, w = tid >> 6;
  const int l15 = lane & 15, l4 = lane >> 4;
  const int h = blockIdx.x;
  const int t = 15 - (int)blockIdx.y;     // heavy q-tiles dispatched first
  const int kvh = h >> 2;
  const int q0 = t * 128;
  const int nt = 2 * t + 2;               // kv tiles to process
  const float scale = 0.08838834764831845f;  // 1/sqrt(128)

  const u16* qb = qkv;            // q section, row stride 6144
  const u16* kb = qkv + 4096;     // k section, row stride 6144

  // Q fragments (B-operand: col=q=l15, k=d at kc*32+l4*8) — same layout as A
  bf16x8 aq[2][4];
#pragma unroll
  for (int m = 0; m < 2; ++m)
#pragma unroll
    for (int kc = 0; kc < 4; ++kc)
      aq[m][kc] = *(const bf16x8*)(qb + (size_t)(q0 + w * 32 + m * 16 + l15) * 6144 +
                                   h * 128 + kc * 32 + l4 * 8);

  f32x4 o[2][8] = {};          // O^T: rows d = n*16+l4*4+r, col q = l15
  float mrun[2], lrun[2];
#pragma unroll
  for (int m = 0; m < 2; ++m) { mrun[m] = -1e30f; lrun[m] = 0.f; }

  auto STAGE = [&](int b, int tt) {
    int s0 = tt * 64;
#pragma unroll
    for (int it = 0; it < 4; ++it) {
      int off = it * 4096 + tid * 16;
      int row = off >> 8;
      int c = ((off >> 4) & 15) ^ (row & 15);
      gload_lds16(kb + (size_t)(s0 + row) * 6144 + kvh * 128 + c * 8, (char*)sK[b] + off);
    }
#pragma unroll
    for (int it = 0; it < 4; ++it) {
      int off = it * 4096 + tid * 16;
      int row = off >> 7;
      int c = ((off >> 4) & 7) ^ (row & 7);
      gload_lds16(vT + (size_t)kvh * 262144 + (size_t)row * 2048 + s0 + c * 8,
                  (char*)sV[b] + off);
    }
  };

  STAGE(0, 0);
  __syncthreads();
  int cur = 0;

  for (int tt = 0; tt < nt; ++tt) {
    if (tt + 1 < nt) STAGE(cur ^ 1, tt + 1);
    int s0 = tt * 64;
    u16* wp = &sP[w][0];

#pragma unroll
    for (int m = 0; m < 2; ++m) {
      const int frow0 = q0 + w * 32 + m * 16;
      if (s0 > frow0 + 15) continue;            // fragment fully masked (wave-uniform)
      const bool has_mask = (s0 + 63 > frow0);
      const int q_abs = frow0 + l15;            // this lane's q row

      // S^T = K Q^T: sf[j] rows s = s0 + 16j + 4*l4 + i, col q = l15
      f32x4 sf[4] = {};
#pragma unroll
      for (int kc = 0; kc < 4; ++kc) {
#pragma unroll
        for (int j = 0; j < 4; ++j) {
          int krow = j * 16 + l15;
          bf16x8 bk = *(const bf16x8*)((char*)sK[cur] + krow * 256 +
                                       (((kc * 4 + l4) ^ (krow & 15)) << 4));
          sf[j] = __builtin_amdgcn_mfma_f32_16x16x32_bf16(bk, aq[m][kc], sf[j], 0, 0, 0);
        }
      }

      // transposed softmax: lane holds 16 P-values of its q-row
      float pv16[4][4];
      float pmax = -1e30f;
#pragma unroll
      for (int j = 0; j < 4; ++j)
#pragma unroll
        for (int i = 0; i < 4; ++i) {
          float v = sf[j][i] * scale;
          if (has_mask && (s0 + 16 * j + 4 * l4 + i) > q_abs) v = -1e9f;
          pv16[j][i] = v;
          pmax = fmaxf(pmax, v);
        }
      pmax = fmaxf(pmax, __shfl_xor(pmax, 16, 64));
      pmax = fmaxf(pmax, __shfl_xor(pmax, 32, 64));
      float mn = fmaxf(mrun[m], pmax);
      float alpha = __expf(mrun[m] - mn);
      mrun[m] = mn;
      float psum = 0.f;
#pragma unroll
      for (int j = 0; j < 4; ++j)
#pragma unroll
        for (int i = 0; i < 4; ++i) {
          float p = __expf(pv16[j][i] - mn);
          pv16[j][i] = p;
          psum += p;
        }
      psum += __shfl_xor(psum, 16, 64);
      psum += __shfl_xor(psum, 32, 64);
      lrun[m] = lrun[m] * alpha + psum;
#pragma unroll
      for (int n = 0; n < 8; ++n)
#pragma unroll
        for (int r = 0; r < 4; ++r) o[m][n][r] *= alpha;

      // store P^T: row q=l15, cols s=16j+4*l4+0..3 packed b64, swizzle ^(q&7)<<4
#pragma unroll
      for (int j = 0; j < 4; ++j) {
        u16x4 pk;
#pragma unroll
        for (int i = 0; i < 4; ++i) pk[i] = f2b(pv16[j][i]);
        int colb = (16 * j + 4 * l4) * 2;
        *(u16x4*)((char*)wp + l15 * 128 + (colb ^ ((l15 & 7) << 4))) = pk;
      }

      // O^T += V^T P^T : A = V^T (row d=l15), B = P^T (col q=l15, k=s)
#pragma unroll
      for (int ks = 0; ks < 2; ++ks) {
        int pcb = (ks * 32 + l4 * 8) * 2;
        bf16x8 pb = *(const bf16x8*)((char*)wp + l15 * 128 + (pcb ^ ((l15 & 7) << 4)));
#pragma unroll
        for (int n = 0; n < 8; ++n) {
          int vrow = n * 16 + l15;
          bf16x8 vv = *(const bf16x8*)((char*)sV[cur] + vrow * 128 +
                                       (((ks * 4 + l4) ^ (vrow & 7)) << 4));
          o[m][n] = __builtin_amdgcn_mfma_f32_16x16x32_bf16(vv, pb, o[m][n], 0, 0, 0);
        }
      }
    }
    __syncthreads();
    cur ^= 1;
  }

  // epilogue: O^T rows d = n*16+l4*4+r, col q = l15; packed 4-wide d writes
#pragma unroll
  for (int m = 0; m < 2; ++m) {
    float rcp = 1.f / lrun[m];
    size_t qrow = (size_t)(q0 + w * 32 + m * 16 + l15);
#pragma unroll
    for (int n = 0; n < 8; ++n) {
      u16x4 pk;
#pragma unroll
      for (int r = 0; r < 4; ++r) pk[r] = f2b(o[m][n][r] * rcp);
      *(u16x4*)(ob + qrow * 4096 + h * 128 + n * 16 + l4 * 4) = pk;
    }
  }
}

extern "C" void kernel_launch(void* const* d_in, const int* in_sizes, int n_in,
                              void* d_out, int out_size, void* d_ws, size_t ws_size,
                              hipStream_t stream) {
  const float* x  = (const float*)d_in[0];
  const float* fc = (const float*)d_in[1];
  const float* fs = (const float*)d_in[2];
  // d_in[3] = mask (causal, hardcoded); d_in[8] = start_pos (0)
  const float* wq = (const float*)d_in[4];
  const float* wk = (const float*)d_in[5];
  const float* wv = (const float*)d_in[6];
  const float* wo = (const float*)d_in[7];
  float* out = (float*)d_out;
  char* ws = (char*)d_ws;

  // workspace layout (~113 MB)
  u16* xb   = (u16*)(ws + 0);               // 16.8 MB  x bf16 [2048][4096]
  u16* qkv  = (u16*)(ws + 16777216);        // 25.2 MB  qkv bf16 [2048][6144]
  u16* ob   = (u16*)(ws + 41943040);        // 16.8 MB  attn out bf16 [2048][4096]
  u16* wT   = (u16*)(ws + 58720256);        // 50.3 MB  w_qkv^T bf16 [6144][4096]
  u16* vT   = (u16*)(ws + 109051904);       //  4.2 MB  v^T bf16 [8][128][2048]
  u16* woT  = wT;                           // reuse (wT dead after qkv GEMM)

  cast_bf16_kernel<<<8192, 256, 0, stream>>>(x, xb);
  wtrans_kernel<<<dim3(128, 128), 256, 0, stream>>>(wq, wT, 4096, 4096);
  wtrans_kernel<<<dim3(32, 128), 256, 0, stream>>>(wk, wT + (size_t)4096 * 4096, 4096, 1024);
  wtrans_kernel<<<dim3(32, 128), 256, 0, stream>>>(wv, wT + (size_t)5120 * 4096, 4096, 1024);

  // fused qkv projection: [2048][6144]; grid 16*48 = 768 (%8==0)
  gemm_bt_kernel<1><<<768, 256, 0, stream>>>(xb, wT, qkv, 2048, 6144, 4096);

  rope_kernel<32, 6144><<<4096, 256, 0, stream>>>(qkv, fc, fs);
  rope_kernel<8, 6144><<<1024, 256, 0, stream>>>(qkv + 4096, fc, fs);
  vtrans_kernel<<<dim3(32, 2, 8), 256, 0, stream>>>(qkv + 5120, vT);

  attn_kernel<<<dim3(32, 16), 256, 0, stream>>>(qkv, vT, ob);

  wtrans_kernel<<<dim3(128, 128), 256, 0, stream>>>(wo, woT, 4096, 4096);
  // out projection: grid 16*32 = 512 (%8==0)
  gemm_bt_kernel<0><<<512, 256, 0, stream>>>(ob, woT, out, 2048, 4096, 4096);
}